// Round 2
// baseline (278.550 us; speedup 1.0000x reference)
//
#include <hip/hip_runtime.h>
#include <stddef.h>

// Problem: B=1, H=16, S=4096, D=64, fp32.
// out = (Q K^T) V == Q (K^T V)   [no softmax -> associativity]
// Single NON-cooperative kernel, 512 blocks x 256 threads.
// Cross-block sync: per-head arrival counters in workspace + spin with
// release/acquire __threadfence(). Deadlock-safe: 2 blocks/CU co-residency
// (LDS 33.8KB -> 4/CU possible, launch_bounds caps at 2/CU needed) AND the
// wait graph only spans each head's own 32-block group.
//   Phase 1: P[h][c] = K_chunk^T V_chunk   (32 chunks/head, 64x64 partials)
//   Phase 2: M[h] = sum_c P[h][c]          (4 reducer blocks per head, c<4)
//   Phase 3: O[h] = Q[h] @ M[h]            (each block: 2 x 64-row chunks)

#define SLEN 4096
#define DIM  64
#define NH   16
#define CH   32            // S-chunks for phase 1
#define RPC  (SLEN / CH)   // 128 rows per chunk

typedef float f4v __attribute__((ext_vector_type(4)));

__device__ __forceinline__ int atomic_read(int* p) { return atomicAdd(p, 0); }

__global__ __launch_bounds__(256, 2) void fused_attn(
    const float* __restrict__ Q, const float* __restrict__ K,
    const float* __restrict__ V, float* __restrict__ O,
    float* __restrict__ P, float* __restrict__ Mbuf, int* __restrict__ cnt)
{
    const int b = blockIdx.x;      // 0..511
    const int t = threadIdx.x;
    const int i = t >> 4;
    const int j = t & 15;
    const int h = b >> 5;          // head: blocks h*32..h*32+31 form one group
    const int c = b & 31;          // chunk within head

    // Phase 1 uses 32x64 K + 32x64 V tiles (16 KB); phase 3 uses 64x68 Q (+pad)
    // + 64x64 M (33.8 KB). One buffer, aliased; phases separated by barriers.
    __shared__ float smem[64 * 68 + 64 * 64];

    // ---------------- Phase 1: P[h][c] = K_chunk^T V_chunk ----------------
    {
        float (*Ks)[64] = reinterpret_cast<float(*)[64]>(smem);
        float (*Vs)[64] = reinterpret_cast<float(*)[64]>(smem + 32 * 64);

        const f4v* K4 = (const f4v*)(K + ((size_t)h * SLEN + (size_t)c * RPC) * DIM);
        const f4v* V4 = (const f4v*)(V + ((size_t)h * SLEN + (size_t)c * RPC) * DIM);

        float acc[4][4] = {{0.f,0.f,0.f,0.f},{0.f,0.f,0.f,0.f},
                           {0.f,0.f,0.f,0.f},{0.f,0.f,0.f,0.f}};

        // staging map: idx = u*256 + t -> row = idx>>4 (0..31), c4 = idx&15
        f4v kst[2], vst[2];
        #pragma unroll
        for (int u = 0; u < 2; ++u) {
            int idx = u * 256 + t, row = idx >> 4, c4 = idx & 15;
            kst[u] = K4[row * 16 + c4];
            vst[u] = V4[row * 16 + c4];
        }

        for (int tile = 0; tile < 4; ++tile) {
            __syncthreads();               // protect previous tile's LDS reads
            #pragma unroll
            for (int u = 0; u < 2; ++u) {
                int idx = u * 256 + t, row = idx >> 4, c4 = idx & 15;
                *(f4v*)&Ks[row][c4 * 4] = kst[u];
                *(f4v*)&Vs[row][c4 * 4] = vst[u];
            }
            __syncthreads();

            if (tile < 3) {                // prefetch next tile under compute
                #pragma unroll
                for (int u = 0; u < 2; ++u) {
                    int idx = u * 256 + t, row = idx >> 4, c4 = idx & 15;
                    kst[u] = K4[((tile + 1) * 32 + row) * 16 + c4];
                    vst[u] = V4[((tile + 1) * 32 + row) * 16 + c4];
                }
            }

            #pragma unroll
            for (int s = 0; s < 32; ++s) {
                f4v kf = *(const f4v*)&Ks[s][i * 4];   // 4 distinct addrs/wave: broadcast
                f4v vf = *(const f4v*)&Vs[s][j * 4];   // 16 distinct, 2-way alias: free
                #pragma unroll
                for (int a = 0; a < 4; ++a)
                    #pragma unroll
                    for (int bb = 0; bb < 4; ++bb)
                        acc[a][bb] = fmaf(kf[a], vf[bb], acc[a][bb]);
            }
        }

        float* Pc = P + ((size_t)h * CH + c) * (DIM * DIM);
        #pragma unroll
        for (int a = 0; a < 4; ++a) {
            f4v r;
            r[0] = acc[a][0]; r[1] = acc[a][1]; r[2] = acc[a][2]; r[3] = acc[a][3];
            *(f4v*)&Pc[(i * 4 + a) * DIM + j * 4] = r;
        }
    }
    __threadfence();                        // release: P visible at agent scope
    __syncthreads();                        // all threads of block fenced
    if (t == 0) atomicAdd(&cnt[h], 1);      // signal P[h][c] ready

    // ---------------- Phase 2: M[h] = sum over 32 chunk-partials ----------------
    // 4 reducer blocks per head (c<4); each thread owns one f4 of M[h].
    if (c < 4) {
        if (t == 0) {
            while (atomic_read(&cnt[h]) < CH) __builtin_amdgcn_s_sleep(2);
        }
        __syncthreads();
        __threadfence();                    // acquire: see other blocks' P stores

        const f4v* Ph = (const f4v*)(P + (size_t)h * CH * DIM * DIM);
        const int off = c * 256 + t;        // f4 index within 64x64 (0..1023)
        f4v sum; sum[0] = 0.f; sum[1] = 0.f; sum[2] = 0.f; sum[3] = 0.f;
        #pragma unroll
        for (int cc = 0; cc < CH; ++cc) {
            f4v x = Ph[cc * (DIM * DIM / 4) + off];
            sum[0] += x[0]; sum[1] += x[1]; sum[2] += x[2]; sum[3] += x[3];
        }
        ((f4v*)(Mbuf + (size_t)h * DIM * DIM))[off] = sum;

        __threadfence();                    // release: M visible at agent scope
        __syncthreads();
        if (t == 0) atomicAdd(&cnt[NH + h], 1);
    }

    // ---------------- Phase 3: O = Q @ M (2 x 64-row chunks per block) ----------------
    {
        // Prefetch first Q sub-chunk into registers BEFORE the spin:
        // HBM latency hides under the wait.
        const f4v* Q4_0 = (const f4v*)(Q + ((size_t)h * SLEN + (size_t)(c * 2) * 64) * DIM);
        f4v qst[4];
        #pragma unroll
        for (int it = 0; it < 4; ++it) qst[it] = Q4_0[it * 256 + t];

        if (t == 0) {
            while (atomic_read(&cnt[NH + h]) < 4) __builtin_amdgcn_s_sleep(2);
        }
        __syncthreads();                    // also protects phase-1 LDS liveness
        __threadfence();                    // acquire: see reducers' M stores

        float (*Qs)[68] = reinterpret_cast<float(*)[68]>(smem);           // +4 pad
        float (*Ms)[64] = reinterpret_cast<float(*)[64]>(smem + 64 * 68);
        const f4v* M4 = (const f4v*)(Mbuf + (size_t)h * DIM * DIM);
        f4v* O4 = (f4v*)O;

        #pragma unroll
        for (int it = 0; it < 4; ++it) {
            int idx = it * 256 + t, row = idx >> 4, c4 = idx & 15;
            *(f4v*)&Ms[row][c4 * 4] = M4[idx];
            *(f4v*)&Qs[row][c4 * 4] = qst[it];
        }
        __syncthreads();

        for (int sub = 0; sub < 2; ++sub) {
            const int chunk = c * 2 + sub;

            if (sub) {                      // stage second Q sub-chunk
                const f4v* Q4 = (const f4v*)(Q + ((size_t)h * SLEN + (size_t)chunk * 64) * DIM);
                f4v q2[4];
                #pragma unroll
                for (int it = 0; it < 4; ++it) q2[it] = Q4[it * 256 + t];
                __syncthreads();            // previous sub's Qs reads done
                #pragma unroll
                for (int it = 0; it < 4; ++it) {
                    int idx = it * 256 + t, row = idx >> 4, c4 = idx & 15;
                    *(f4v*)&Qs[row][c4 * 4] = q2[it];
                }
                __syncthreads();
            }

            float acc[4][4] = {{0.f,0.f,0.f,0.f},{0.f,0.f,0.f,0.f},
                               {0.f,0.f,0.f,0.f},{0.f,0.f,0.f,0.f}};

            for (int d0 = 0; d0 < DIM; d0 += 4) {
                f4v qf[4], mf[4];
                #pragma unroll
                for (int a = 0; a < 4; ++a)
                    qf[a] = *(const f4v*)&Qs[i * 4 + a][d0];
                #pragma unroll
                for (int cc = 0; cc < 4; ++cc)
                    mf[cc] = *(const f4v*)&Ms[d0 + cc][j * 4];
                #pragma unroll
                for (int a = 0; a < 4; ++a)
                    #pragma unroll
                    for (int cc = 0; cc < 4; ++cc)
                        #pragma unroll
                        for (int bb = 0; bb < 4; ++bb)
                            acc[a][bb] = fmaf(qf[a][cc], mf[cc][bb], acc[a][bb]);
            }

            #pragma unroll
            for (int a = 0; a < 4; ++a) {
                f4v res;
                res[0] = acc[a][0]; res[1] = acc[a][1]; res[2] = acc[a][2]; res[3] = acc[a][3];
                O4[((size_t)h * SLEN + (size_t)chunk * 64 + i * 4 + a) * (DIM / 4) + j] = res;
            }
        }
    }
}

extern "C" void kernel_launch(void* const* d_in, const int* in_sizes, int n_in,
                              void* d_out, int out_size, void* d_ws, size_t ws_size,
                              hipStream_t stream) {
    const float* q = (const float*)d_in[0];
    const float* k = (const float*)d_in[1];
    const float* v = (const float*)d_in[2];
    float* out = (float*)d_out;

    int*   cnt = (int*)d_ws;                                   // 2*NH ints, pad to 256 B
    float* P   = (float*)d_ws + 64;                            // 8 MiB of partials
    float* M   = P + (size_t)NH * CH * DIM * DIM;              // 256 KiB

    // Workspace is poisoned by the harness each iteration -> re-zero counters.
    hipMemsetAsync(d_ws, 0, 256, stream);

    fused_attn<<<dim3(512), dim3(256), 0, stream>>>(q, k, v, out, P, M, cnt);
}

// Round 3
// 256.393 us; speedup vs baseline: 1.0864x; 1.0864x over previous
//
#include <hip/hip_runtime.h>
#include <stddef.h>

// Problem: B=1, H=16, S=4096, D=64, fp32.
// out = (Q K^T) V == Q (K^T V)   [no softmax -> associativity]
// Single NON-cooperative kernel, 512 blocks x 256 threads.
// Cross-block sync: per-head arrival counters (one 256-B line EACH -> no
// false sharing) + relaxed atomic-LOAD polling (no RMW spin-storm) +
// release/acquire __threadfence(). Deadlock-safe: all waits are contained
// within each head's own 32-block group, and 512 blocks co-reside
// (LDS 33.8 KB -> 4 blocks/CU possible; we need 2).
//   Phase 1: P[h][c] = K_chunk^T V_chunk   (32 chunks/head, 64x64 partials)
//   Phase 2: M[h] = sum_c P[h][c]          (4 reducer blocks per head, c<4)
//   Phase 3: O[h] = Q[h] @ M[h]            (each block: 2 x 64-row chunks)

#define SLEN 4096
#define DIM  64
#define NH   16
#define CH   32            // S-chunks for phase 1
#define RPC  (SLEN / CH)   // 128 rows per chunk
#define CSTRIDE 64         // ints per counter slot = 256 B, one line per counter

typedef float f4v __attribute__((ext_vector_type(4)));

__device__ __forceinline__ int poll_load(const int* p) {
    return __hip_atomic_load(p, __ATOMIC_RELAXED, __HIP_MEMORY_SCOPE_AGENT);
}

__global__ __launch_bounds__(256, 2) void fused_attn(
    const float* __restrict__ Q, const float* __restrict__ K,
    const float* __restrict__ V, float* __restrict__ O,
    float* __restrict__ P, float* __restrict__ Mbuf, int* __restrict__ cnt)
{
    const int b = blockIdx.x;      // 0..511
    const int t = threadIdx.x;
    const int i = t >> 4;
    const int j = t & 15;
    const int h = b >> 5;          // head: blocks h*32..h*32+31 form one group
    const int c = b & 31;          // chunk within head

    int* arrive1 = &cnt[h * CSTRIDE];             // P[h][*] ready count
    int* arrive2 = &cnt[(NH + h) * CSTRIDE];      // M[h] slice ready count

    // Phase 1 uses 32x64 K + 32x64 V tiles (16 KB); phase 3 uses 64x68 Q (+pad)
    // + 64x64 M (33.8 KB). One buffer, aliased; phases separated by barriers.
    __shared__ float smem[64 * 68 + 64 * 64];

    // ---------------- Phase 1: P[h][c] = K_chunk^T V_chunk ----------------
    {
        float (*Ks)[64] = reinterpret_cast<float(*)[64]>(smem);
        float (*Vs)[64] = reinterpret_cast<float(*)[64]>(smem + 32 * 64);

        const f4v* K4 = (const f4v*)(K + ((size_t)h * SLEN + (size_t)c * RPC) * DIM);
        const f4v* V4 = (const f4v*)(V + ((size_t)h * SLEN + (size_t)c * RPC) * DIM);

        float acc[4][4] = {{0.f,0.f,0.f,0.f},{0.f,0.f,0.f,0.f},
                           {0.f,0.f,0.f,0.f},{0.f,0.f,0.f,0.f}};

        // staging map: idx = u*256 + t -> row = idx>>4 (0..31), c4 = idx&15
        f4v kst[2], vst[2];
        #pragma unroll
        for (int u = 0; u < 2; ++u) {
            int idx = u * 256 + t, row = idx >> 4, c4 = idx & 15;
            kst[u] = K4[row * 16 + c4];
            vst[u] = V4[row * 16 + c4];
        }

        for (int tile = 0; tile < 4; ++tile) {
            __syncthreads();               // protect previous tile's LDS reads
            #pragma unroll
            for (int u = 0; u < 2; ++u) {
                int idx = u * 256 + t, row = idx >> 4, c4 = idx & 15;
                *(f4v*)&Ks[row][c4 * 4] = kst[u];
                *(f4v*)&Vs[row][c4 * 4] = vst[u];
            }
            __syncthreads();

            if (tile < 3) {                // prefetch next tile under compute
                #pragma unroll
                for (int u = 0; u < 2; ++u) {
                    int idx = u * 256 + t, row = idx >> 4, c4 = idx & 15;
                    kst[u] = K4[((tile + 1) * 32 + row) * 16 + c4];
                    vst[u] = V4[((tile + 1) * 32 + row) * 16 + c4];
                }
            }

            #pragma unroll
            for (int s = 0; s < 32; ++s) {
                f4v kf = *(const f4v*)&Ks[s][i * 4];   // 4 distinct addrs/wave: broadcast
                f4v vf = *(const f4v*)&Vs[s][j * 4];   // 16 distinct, 2-way alias: free
                #pragma unroll
                for (int a = 0; a < 4; ++a)
                    #pragma unroll
                    for (int bb = 0; bb < 4; ++bb)
                        acc[a][bb] = fmaf(kf[a], vf[bb], acc[a][bb]);
            }
        }

        float* Pc = P + ((size_t)h * CH + c) * (DIM * DIM);
        #pragma unroll
        for (int a = 0; a < 4; ++a) {
            f4v r;
            r[0] = acc[a][0]; r[1] = acc[a][1]; r[2] = acc[a][2]; r[3] = acc[a][3];
            *(f4v*)&Pc[(i * 4 + a) * DIM + j * 4] = r;
        }
    }
    __threadfence();                        // release: P visible at agent scope
    __syncthreads();                        // all threads of block fenced
    if (t == 0) atomicAdd(arrive1, 1);      // signal P[h][c] ready

    // ---------------- Phase 2: M[h] = sum over 32 chunk-partials ----------------
    // 4 reducer blocks per head (c<4); each thread owns one f4 of M[h].
    if (c < 4) {
        if (t == 0) {
            while (poll_load(arrive1) < CH) __builtin_amdgcn_s_sleep(4);
        }
        __syncthreads();
        __threadfence();                    // acquire: see other blocks' P stores

        const f4v* Ph = (const f4v*)(P + (size_t)h * CH * DIM * DIM);
        const int off = c * 256 + t;        // f4 index within 64x64 (0..1023)
        f4v sum; sum[0] = 0.f; sum[1] = 0.f; sum[2] = 0.f; sum[3] = 0.f;
        #pragma unroll
        for (int cc = 0; cc < CH; ++cc) {
            f4v x = Ph[cc * (DIM * DIM / 4) + off];
            sum[0] += x[0]; sum[1] += x[1]; sum[2] += x[2]; sum[3] += x[3];
        }
        ((f4v*)(Mbuf + (size_t)h * DIM * DIM))[off] = sum;

        __threadfence();                    // release: M visible at agent scope
        __syncthreads();
        if (t == 0) atomicAdd(arrive2, 1);
    }

    // ---------------- Phase 3: O = Q @ M (2 x 64-row chunks per block) ----------------
    {
        // Prefetch first Q sub-chunk into registers BEFORE the spin:
        // HBM latency hides under the wait.
        const f4v* Q4_0 = (const f4v*)(Q + ((size_t)h * SLEN + (size_t)(c * 2) * 64) * DIM);
        f4v qst[4];
        #pragma unroll
        for (int it = 0; it < 4; ++it) qst[it] = Q4_0[it * 256 + t];

        if (t == 0) {
            while (poll_load(arrive2) < 4) __builtin_amdgcn_s_sleep(4);
        }
        __syncthreads();                    // also protects phase-1 LDS liveness
        __threadfence();                    // acquire: see reducers' M stores

        float (*Qs)[68] = reinterpret_cast<float(*)[68]>(smem);           // +4 pad
        float (*Ms)[64] = reinterpret_cast<float(*)[64]>(smem + 64 * 68);
        const f4v* M4 = (const f4v*)(Mbuf + (size_t)h * DIM * DIM);
        f4v* O4 = (f4v*)O;

        #pragma unroll
        for (int it = 0; it < 4; ++it) {
            int idx = it * 256 + t, row = idx >> 4, c4 = idx & 15;
            *(f4v*)&Ms[row][c4 * 4] = M4[idx];
            *(f4v*)&Qs[row][c4 * 4] = qst[it];
        }
        __syncthreads();

        for (int sub = 0; sub < 2; ++sub) {
            const int chunk = c * 2 + sub;

            if (sub) {                      // stage second Q sub-chunk
                const f4v* Q4 = (const f4v*)(Q + ((size_t)h * SLEN + (size_t)chunk * 64) * DIM);
                f4v q2[4];
                #pragma unroll
                for (int it = 0; it < 4; ++it) q2[it] = Q4[it * 256 + t];
                __syncthreads();            // previous sub's Qs reads done
                #pragma unroll
                for (int it = 0; it < 4; ++it) {
                    int idx = it * 256 + t, row = idx >> 4, c4 = idx & 15;
                    *(f4v*)&Qs[row][c4 * 4] = q2[it];
                }
                __syncthreads();
            }

            float acc[4][4] = {{0.f,0.f,0.f,0.f},{0.f,0.f,0.f,0.f},
                               {0.f,0.f,0.f,0.f},{0.f,0.f,0.f,0.f}};

            for (int d0 = 0; d0 < DIM; d0 += 4) {
                f4v qf[4], mf[4];
                #pragma unroll
                for (int a = 0; a < 4; ++a)
                    qf[a] = *(const f4v*)&Qs[i * 4 + a][d0];
                #pragma unroll
                for (int cc = 0; cc < 4; ++cc)
                    mf[cc] = *(const f4v*)&Ms[d0 + cc][j * 4];
                #pragma unroll
                for (int a = 0; a < 4; ++a)
                    #pragma unroll
                    for (int cc = 0; cc < 4; ++cc)
                        #pragma unroll
                        for (int bb = 0; bb < 4; ++bb)
                            acc[a][bb] = fmaf(qf[a][cc], mf[cc][bb], acc[a][bb]);
            }

            #pragma unroll
            for (int a = 0; a < 4; ++a) {
                f4v res;
                res[0] = acc[a][0]; res[1] = acc[a][1]; res[2] = acc[a][2]; res[3] = acc[a][3];
                O4[((size_t)h * SLEN + (size_t)chunk * 64 + i * 4 + a) * (DIM / 4) + j] = res;
            }
        }
    }
}

extern "C" void kernel_launch(void* const* d_in, const int* in_sizes, int n_in,
                              void* d_out, int out_size, void* d_ws, size_t ws_size,
                              hipStream_t stream) {
    const float* q = (const float*)d_in[0];
    const float* k = (const float*)d_in[1];
    const float* v = (const float*)d_in[2];
    float* out = (float*)d_out;

    int*   cnt = (int*)d_ws;                                   // 32 slots x 256 B = 8 KB
    float* P   = (float*)d_ws + 2 * NH * CSTRIDE;              // 8 MiB of partials
    float* M   = P + (size_t)NH * CH * DIM * DIM;              // 256 KiB

    // Workspace is poisoned by the harness each iteration -> re-zero counters.
    hipMemsetAsync(d_ws, 0, 2 * NH * CSTRIDE * sizeof(int), stream);

    fused_attn<<<dim3(512), dim3(256), 0, stream>>>(q, k, v, out, P, M, cnt);
}

// Round 4
// 104.785 us; speedup vs baseline: 2.6583x; 2.4468x over previous
//
#include <hip/hip_runtime.h>
#include <stddef.h>

// Problem: B=1, H=16, S=4096, D=64, fp32.
// out = (Q K^T) V  ==  Q (K^T V)   [no softmax -> associativity]
// Three-kernel pipeline (proven 109 us end-to-end; fused/spin variants measured
// 185-195 us due to unexplained intra-dispatch cross-XCD sync cost -> reverted).
// Stage 1: P[h][c] = K_chunk^T V_chunk  (64x64 partials, no atomics)
// Stage 2: M[h] = sum_c P[h][c]         (256 blocks x 1 wave, f4 streaming)
// Stage 3: O[h] = Q[h] @ M[h]

#define SLEN 4096
#define DIM  64
#define NH   16
#define CH   32            // S-chunks for stage 1
#define RPC  (SLEN / CH)   // 128 rows per chunk

typedef float f4v __attribute__((ext_vector_type(4)));

// ---------------- Kernel A: partial M = K^T V over a 128-row chunk ----------------
// grid (32, 16), 256 threads. Thread (i=t>>4, j=t&15) owns a 4x4 tile of the 64x64 partial.
// 32-row LDS tiles, register-prefetch of tile t+1 overlaps compute of tile t.
__global__ __launch_bounds__(256) void kvT_partial(const float* __restrict__ K,
                                                   const float* __restrict__ V,
                                                   float* __restrict__ P) {
    const int c = blockIdx.x;
    const int h = blockIdx.y;
    const int t = threadIdx.x;
    const int i = t >> 4;
    const int j = t & 15;

    __shared__ float Ks[32][64];
    __shared__ float Vs[32][64];

    const f4v* K4 = (const f4v*)(K + ((size_t)h * SLEN + (size_t)c * RPC) * DIM);
    const f4v* V4 = (const f4v*)(V + ((size_t)h * SLEN + (size_t)c * RPC) * DIM);

    float acc[4][4] = {{0.f,0.f,0.f,0.f},{0.f,0.f,0.f,0.f},
                       {0.f,0.f,0.f,0.f},{0.f,0.f,0.f,0.f}};

    // staging map: idx = u*256 + t -> row = idx>>4 (0..31), c4 = idx&15
    f4v kst[2], vst[2];
    #pragma unroll
    for (int u = 0; u < 2; ++u) {
        int idx = u * 256 + t, row = idx >> 4, c4 = idx & 15;
        kst[u] = K4[row * 16 + c4];
        vst[u] = V4[row * 16 + c4];
    }

    for (int tile = 0; tile < 4; ++tile) {
        __syncthreads();               // protect previous tile's LDS reads
        #pragma unroll
        for (int u = 0; u < 2; ++u) {
            int idx = u * 256 + t, row = idx >> 4, c4 = idx & 15;
            *(f4v*)&Ks[row][c4 * 4] = kst[u];
            *(f4v*)&Vs[row][c4 * 4] = vst[u];
        }
        __syncthreads();

        if (tile < 3) {                // prefetch next tile: latency hides under compute
            #pragma unroll
            for (int u = 0; u < 2; ++u) {
                int idx = u * 256 + t, row = idx >> 4, c4 = idx & 15;
                kst[u] = K4[((tile + 1) * 32 + row) * 16 + c4];
                vst[u] = V4[((tile + 1) * 32 + row) * 16 + c4];
            }
        }

        #pragma unroll
        for (int s = 0; s < 32; ++s) {
            f4v kf = *(const f4v*)&Ks[s][i * 4];   // 4 distinct addrs/wave -> broadcast, free
            f4v vf = *(const f4v*)&Vs[s][j * 4];   // 16 distinct, 2-way bank alias -> free
            #pragma unroll
            for (int a = 0; a < 4; ++a)
                #pragma unroll
                for (int b = 0; b < 4; ++b)
                    acc[a][b] = fmaf(kf[a], vf[b], acc[a][b]);
        }
    }

    float* Pc = P + ((size_t)h * CH + c) * (DIM * DIM);
    #pragma unroll
    for (int a = 0; a < 4; ++a) {
        f4v r;
        r[0] = acc[a][0]; r[1] = acc[a][1]; r[2] = acc[a][2]; r[3] = acc[a][3];
        *(f4v*)&Pc[(i * 4 + a) * DIM + j * 4] = r;
    }
}

// ---------------- Kernel R: M[h] = sum over 32 chunk-partials ----------------
// grid (16, 16), 64 threads (1 wave). Each thread owns one f4 of the head's
// 64x64 M and sums 32 independent, fully-pipelined coalesced loads
// (64 lanes x 16 B = 1 KB per access). 256 blocks -> 1 per CU, 4x the
// latency-hiding of the old 64-block shape at identical traffic.
__global__ __launch_bounds__(64) void reduceM(const float* __restrict__ P,
                                              float* __restrict__ M) {
    const int g = blockIdx.x;          // 0..15: which 64-f4 slice of the head
    const int h = blockIdx.y;
    const int t = threadIdx.x;         // 0..63
    const int off = g * 64 + t;        // f4 index within 64x64 (0..1023)

    const f4v* Ph = (const f4v*)(P + (size_t)h * CH * DIM * DIM);
    f4v sum; sum[0] = 0.f; sum[1] = 0.f; sum[2] = 0.f; sum[3] = 0.f;
    #pragma unroll
    for (int c = 0; c < CH; ++c) {
        f4v x = Ph[(size_t)c * (DIM * DIM / 4) + off];
        sum[0] += x[0]; sum[1] += x[1]; sum[2] += x[2]; sum[3] += x[3];
    }
    ((f4v*)(M + (size_t)h * DIM * DIM))[off] = sum;
}

// ---------------- Kernel B: O = Q @ M (per head) ----------------
// grid (64, 16), 256 threads. Thread (i,j) computes a 4x4 tile of a 64x64 output chunk.
__global__ __launch_bounds__(256) void qm_kernel(const float* __restrict__ Q,
                                                 const float* __restrict__ M,
                                                 float* __restrict__ O) {
    const int chunk = blockIdx.x;
    const int h     = blockIdx.y;
    const int t     = threadIdx.x;
    const int i     = t >> 4;
    const int j     = t & 15;

    __shared__ float Qs[64][68];       // +4 pad keeps 16B alignment, breaks bank conflicts
    __shared__ float Ms[64][64];

    const f4v* Q4 = (const f4v*)(Q + ((size_t)h * SLEN + (size_t)chunk * 64) * DIM);
    const f4v* M4 = (const f4v*)(M + (size_t)h * DIM * DIM);

    #pragma unroll
    for (int it = 0; it < 4; ++it) {
        int idx = it * 256 + t;        // 0..1023 f4s
        int row = idx >> 4;
        int c4  = idx & 15;
        *(f4v*)&Qs[row][c4 * 4] = Q4[idx];
        *(f4v*)&Ms[row][c4 * 4] = M4[idx];
    }
    __syncthreads();

    float acc[4][4] = {{0.f,0.f,0.f,0.f},{0.f,0.f,0.f,0.f},
                       {0.f,0.f,0.f,0.f},{0.f,0.f,0.f,0.f}};

    for (int d0 = 0; d0 < DIM; d0 += 4) {
        f4v qf[4], mf[4];
        #pragma unroll
        for (int a = 0; a < 4; ++a)
            qf[a] = *(const f4v*)&Qs[i * 4 + a][d0];
        #pragma unroll
        for (int cc = 0; cc < 4; ++cc)
            mf[cc] = *(const f4v*)&Ms[d0 + cc][j * 4];
        #pragma unroll
        for (int a = 0; a < 4; ++a)
            #pragma unroll
            for (int cc = 0; cc < 4; ++cc)
                #pragma unroll
                for (int b = 0; b < 4; ++b)
                    acc[a][b] = fmaf(qf[a][cc], mf[cc][b], acc[a][b]);
    }

    f4v* O4 = (f4v*)O;
    #pragma unroll
    for (int a = 0; a < 4; ++a) {
        f4v res;
        res[0] = acc[a][0]; res[1] = acc[a][1]; res[2] = acc[a][2]; res[3] = acc[a][3];
        O4[((size_t)h * SLEN + (size_t)chunk * 64 + i * 4 + a) * (DIM / 4) + j] = res;
    }
}

extern "C" void kernel_launch(void* const* d_in, const int* in_sizes, int n_in,
                              void* d_out, int out_size, void* d_ws, size_t ws_size,
                              hipStream_t stream) {
    const float* q = (const float*)d_in[0];
    const float* k = (const float*)d_in[1];
    const float* v = (const float*)d_in[2];
    float* out = (float*)d_out;
    float* P = (float*)d_ws;                                   // 16*32*4096 floats = 8 MiB
    float* M = P + (size_t)NH * CH * DIM * DIM;                // 256 KiB

    kvT_partial<<<dim3(CH, NH), 256, 0, stream>>>(k, v, P);
    reduceM<<<dim3(16, NH), 64, 0, stream>>>(P, M);
    qm_kernel<<<dim3(64, NH), 256, 0, stream>>>(q, M, out);
}